// Round 3
// baseline (150.468 us; speedup 1.0000x reference)
//
#include <hip/hip_runtime.h>

#define ALG_DIM 248
#define ROWS 32                    // rows per main-kernel block
#define KSPLIT 4
#define KPB 62                     // k-slots per block (248/4)
#define CAP 256                    // uint2 capacity per bucket (pow2; max bucket ~160)
#define CNT_STRIDE 16              // ints between cursors (64 B -> spread L2 lines)
#define PLSTRIDE_B 3984            // plane stride bytes (248*16 + 16; /4 = 996 ≡ 4 mod 32)
#define PLSTRIDE_DW 996

typedef __fp16 h2v __attribute__((ext_vector_type(2)));
union H2U { unsigned u; h2v h; };

// ---------- prep: ONE kernel, no memset, no global cursors ----------
// 62 blocks; block b OWNS buckets k in [4b, 4b+4). Each block scans idx_k
// (30000 coalesced ints = 120 KB), keeps its ~484 entries, allocates
// positions from LDS counters (zero-init in-kernel), writes packed entries,
// then zeroes its buckets' tails [size, CAP) and stores cnt[k] (sole owner,
// plain store). Zero tail entries are exact no-ops in k_main (c=0 -> +0).
// No pre-zeroed workspace required anywhere -> the memset node is gone.

__global__ __launch_bounds__(256) void k_scatter_own(
    const int* __restrict__ idx_i, const int* __restrict__ idx_j,
    const int* __restrict__ idx_k, const float* __restrict__ coeff,
    int* __restrict__ cnt, uint2* __restrict__ packed, int nnz)
{
    __shared__ int lcnt[4];
    const int tid = threadIdx.x;
    const int bx  = blockIdx.x;
    const int kb  = bx << 2;

    if (tid < 4) lcnt[tid] = 0;
    __syncthreads();

    for (int t = tid; t < nnz; t += 256) {
        const int k = idx_k[t];
        if ((k >> 2) == bx) {
            const int pos = atomicAdd(&lcnt[k & 3], 1);
            if (pos < CAP) {                       // structurally unreachable
                const float c = coeff[t];
                H2U hc; hc.h = __builtin_amdgcn_cvt_pkrtz(c, c);
                uint2 p;
                p.x = ((unsigned)idx_i[t] << 4) | ((unsigned)idx_j[t] << 20);
                p.y = hc.u;
                packed[((size_t)k << 8) + pos] = p;
            }
        }
    }
    __syncthreads();

    // tail-zero my 4 buckets (covers wave-max trip + 1-uint4 prefetch over-read)
    for (int b = 0; b < 4; ++b) {
        const int k  = kb + b;
        const int sz = min(lcnt[b], CAP);
        for (int e = sz + tid; e < CAP; e += 256)
            packed[((size_t)k << 8) + e] = make_uint2(0u, 0u);
    }
    if (tid < 4) cnt[(kb + tid) * CNT_STRIDE] = lcnt[tid];
}

// ---------- main: plane-layout f16 gather, packed FMA, windowed fp32 flush ----
// (byte-for-byte the round-1 kernel: verified, 0 bank conflicts, LDS-bound)
// 256 threads = 64 streams x 4 lanes over 32 rows x 62 slots. x,y in LDS as
// f16 in 4 planes: (col i, rows 8s..8s+7) at byte s*3984 + i*16. Lane q folds
// q*3984 into its base pointer once; gather = ds_read_b128 at base + i*16.
// Body: 12 VALU/triple + 2 b128. f16 accs flushed to fp32 every 32 triples.
// trip = round8(wave-max of 16 stream sizes) via 4x shfl_xor.

__global__ __launch_bounds__(256, 4) void k_main(
    const float* __restrict__ x, const float* __restrict__ y,
    const uint4* __restrict__ packed4,
    const int* __restrict__ cnt,
    const float* __restrict__ alpha_p, float* __restrict__ out)
{
    __shared__ __align__(16) unsigned xs32[4 * PLSTRIDE_DW];
    __shared__ __align__(16) unsigned ys32[4 * PLSTRIDE_DW];

    const int tid = threadIdx.x;
    const int r0  = blockIdx.x * ROWS;

    for (int u = tid; u < (ALG_DIM / 4) * (ROWS / 2); u += 256) {
        const int rp = u & 15;
        const int cq = u >> 4;
        const size_t ra = (size_t)(r0 + 2 * rp) * ALG_DIM + 4 * cq;
        const float4 xa = *reinterpret_cast<const float4*>(x + ra);
        const float4 xb = *reinterpret_cast<const float4*>(x + ra + ALG_DIM);
        const float4 ya = *reinterpret_cast<const float4*>(y + ra);
        const float4 yb = *reinterpret_cast<const float4*>(y + ra + ALG_DIM);
        const int pbase = (rp >> 2) * PLSTRIDE_DW + (rp & 3);
#define STG(d, XA, XB, YA, YB)                                                  \
        {                                                                       \
            const int dw = pbase + (4 * cq + (d)) * 4;                          \
            H2U hx; hx.h = __builtin_amdgcn_cvt_pkrtz(XA, XB);                  \
            H2U hy; hy.h = __builtin_amdgcn_cvt_pkrtz(YA, YB);                  \
            xs32[dw] = hx.u;                                                    \
            ys32[dw] = hy.u;                                                    \
        }
        STG(0, xa.x, xb.x, ya.x, yb.x)
        STG(1, xa.y, xb.y, ya.y, yb.y)
        STG(2, xa.z, xb.z, ya.z, yb.z)
        STG(3, xa.w, xb.w, ya.w, yb.w)
#undef STG
    }
    __syncthreads();

    const float alpha = alpha_p[0];
    const int   S     = tid >> 2;            // stream 0..63 (owns one slot)
    const int   q     = tid & 3;             // my plane (rows 8q..8q+7)

    const char* xsb = reinterpret_cast<const char*>(xs32) + q * PLSTRIDE_B;
    const char* ysb = reinterpret_cast<const char*>(ys32) + q * PLSTRIDE_B;

    // per-stream bucket size; wave-max over the 16 streams of this wave.
    // Computed by ALL lanes (streams >= KPB contribute 0) so the shuffles
    // run fully converged.
    const int p   = blockIdx.y * KPB + S;
    int m = (S < KPB) ? cnt[p * CNT_STRIDE] : 0;
    m = max(m, __shfl_xor(m, 4));
    m = max(m, __shfl_xor(m, 8));
    m = max(m, __shfl_xor(m, 16));
    m = max(m, __shfl_xor(m, 32));
    const int trip = __builtin_amdgcn_readfirstlane(min((m + 7) & ~7, CAP - 8));
    const int nH   = trip >> 1;              // uint4s (2 triples each)

    if (S < KPB) {
        const int k = p;                     // identity perm
        const uint4* tp = packed4 + ((size_t)p << 7);   // 128 uint4 per bucket

        float a0 = 0.f, a1 = 0.f, a2 = 0.f, a3 = 0.f,
              a4 = 0.f, a5 = 0.f, a6 = 0.f, a7 = 0.f;

        uint4 cur = tp[0];

#define PROC(PW, PC)                                                            \
        {                                                                       \
            const unsigned ox = (PW) & 0xFFFFu;                                 \
            const unsigned oy = (PW) >> 16;                                     \
            const uint4 wx = *reinterpret_cast<const uint4*>(xsb + ox);         \
            const uint4 wy = *reinterpret_cast<const uint4*>(ysb + oy);         \
            H2U cc; cc.u = (PC);                                                \
            H2U ux, uy;                                                         \
            ux.u = wx.x; uy.u = wy.x; c0 = (ux.h * uy.h) * cc.h + c0;           \
            ux.u = wx.y; uy.u = wy.y; c1 = (ux.h * uy.h) * cc.h + c1;           \
            ux.u = wx.z; uy.u = wy.z; c2 = (ux.h * uy.h) * cc.h + c2;           \
            ux.u = wx.w; uy.u = wy.w; c3 = (ux.h * uy.h) * cc.h + c3;           \
        }

        for (int chunk = 0; chunk < nH; chunk += 16) {       // 32-triple window
            h2v c0 = (h2v)0.0f, c1 = (h2v)0.0f, c2 = (h2v)0.0f, c3 = (h2v)0.0f;
            const int hend = min(chunk + 16, nH);
#pragma unroll 2
            for (int h = chunk; h < hend; ++h) {
                const uint4 nxt = tp[h + 1];  // prefetch (zeroed tail covers over-read)
                PROC(cur.x, cur.y)
                PROC(cur.z, cur.w)
                cur = nxt;
            }
            a0 += (float)c0.x; a1 += (float)c0.y;
            a2 += (float)c1.x; a3 += (float)c1.y;
            a4 += (float)c2.x; a5 += (float)c2.y;
            a6 += (float)c3.x; a7 += (float)c3.y;
        }
#undef PROC

        const int rbase = r0 + (q << 3);
        out[(size_t)(rbase + 0) * ALG_DIM + k] = alpha * a0;
        out[(size_t)(rbase + 1) * ALG_DIM + k] = alpha * a1;
        out[(size_t)(rbase + 2) * ALG_DIM + k] = alpha * a2;
        out[(size_t)(rbase + 3) * ALG_DIM + k] = alpha * a3;
        out[(size_t)(rbase + 4) * ALG_DIM + k] = alpha * a4;
        out[(size_t)(rbase + 5) * ALG_DIM + k] = alpha * a5;
        out[(size_t)(rbase + 6) * ALG_DIM + k] = alpha * a6;
        out[(size_t)(rbase + 7) * ALG_DIM + k] = alpha * a7;
    }
}

// ---------- launch: exactly TWO nodes, no memset ----------

extern "C" void kernel_launch(void* const* d_in, const int* in_sizes, int n_in,
                              void* d_out, int out_size, void* d_ws, size_t ws_size,
                              hipStream_t stream) {
    const float* x      = (const float*)d_in[0];
    const float* y      = (const float*)d_in[1];
    const int*   idx_i  = (const int*)d_in[2];
    const int*   idx_j  = (const int*)d_in[3];
    const int*   idx_k  = (const int*)d_in[4];
    const float* coeff  = (const float*)d_in[5];
    const float* alpha  = (const float*)d_in[6];
    float*       out    = (float*)d_out;

    const int nnz   = in_sizes[2];
    const int batch = in_sizes[0] / ALG_DIM;

    // ws: [cnt @0, 16 KB][packed @16384, 248*256*8 = 507904 B]
    char*  ws     = (char*)d_ws;
    int*   cnt    = (int*)ws;
    uint2* packed = (uint2*)(ws + 16384);

    k_scatter_own<<<KPB, 256, 0, stream>>>(idx_i, idx_j, idx_k, coeff,
                                           cnt, packed, nnz);

    dim3 grid(batch / ROWS, KSPLIT);
    k_main<<<grid, 256, 0, stream>>>(x, y, (const uint4*)packed, cnt, alpha, out);
}

// Round 4
// 138.784 us; speedup vs baseline: 1.0842x; 1.0842x over previous
//
#include <hip/hip_runtime.h>

#define ALG_DIM 248
#define ROWS 32                    // rows per main-kernel block
#define KSPLIT 4
#define KPB 62                     // k-slots per block (248/4)
#define CAP 256                    // uint2 capacity per bucket (pow2; max bucket ~160)
#define CB 32                      // prep chunk blocks
#define CNT_STRIDE 16              // ints between cnt entries (64 B)
#define PLSTRIDE_B 3984            // plane stride bytes (248*16 + 16; /4 = 996 ≡ 4 mod 32)
#define PLSTRIDE_DW 996

typedef __fp16 h2v __attribute__((ext_vector_type(2)));
union H2U { unsigned u; h2v h; };

// ---------- prep: ONE kernel, 2 nodes total, no memset, no global atomics ----
// Prefix-scan scatter. 32 blocks; block b:
//   phase 1: scan idx_k[0, lo_b) into an LDS histogram seeded with bucket
//            bases (cur[k] = k*CAP) -> deterministic start cursors. No global
//            state consumed => poison-safe with zero pre-init.
//   phase 2: scatter own chunk [lo_b, hi_b) via LDS atomicAdd -> positions
//            are exactly the original t-order (deterministic sums).
//   phase 3 (last block only): cur[k]-k*CAP == FINAL bucket sizes (its prefix
//            covered all earlier chunks). Zero bucket tails [sz, E) -- these
//            addresses are beyond every block's writes, so no cross-block
//            race -- and store cnt[k] with a plain store.
// Zero tail entries are exact no-ops in k_main (c=0 -> +0).

__global__ __launch_bounds__(256) void k_prep(
    const int* __restrict__ idx_i, const int* __restrict__ idx_j,
    const int* __restrict__ idx_k, const float* __restrict__ coeff,
    int* __restrict__ cnt, uint2* __restrict__ packed, int nnz)
{
    __shared__ int cur[256];
    __shared__ int red[256];
    const int tid = threadIdx.x;
    const int b   = blockIdx.x;

    cur[tid] = tid * CAP;                      // bucket base seeds
    __syncthreads();

    const int chunk = (nnz + CB - 1) / CB;
    const int lo = b * chunk;
    const int hi = min(nnz, lo + chunk);

    // phase 1: prefix histogram over [0, lo)
    for (int t = tid; t < lo; t += 256)
        atomicAdd(&cur[idx_k[t]], 1);
    __syncthreads();                           // all prefix adds before scatter

    // phase 2: scatter own chunk (LDS cursor allocation, deterministic)
    for (int t = lo + tid; t < hi; t += 256) {
        const int k   = idx_k[t];
        const int pos = atomicAdd(&cur[k], 1);
        if (pos < (k + 1) * CAP) {             // structurally unreachable guard
            const float c = coeff[t];
            H2U hc; hc.h = __builtin_amdgcn_cvt_pkrtz(c, c);
            uint2 p;
            p.x = ((unsigned)idx_i[t] << 4) | ((unsigned)idx_j[t] << 20);
            p.y = hc.u;
            packed[pos] = p;
        }
    }

    // phase 3: last block owns tail-zero + cnt store
    if (b == CB - 1) {
        __syncthreads();
        const int sz = (tid < ALG_DIM) ? (cur[tid] - tid * CAP) : 0;
        red[tid] = sz;
        __syncthreads();
        for (int off = 128; off > 0; off >>= 1) {
            if (tid < off) red[tid] = max(red[tid], red[tid + off]);
            __syncthreads();
        }
        const int E = min(CAP, ((red[0] + 7) & ~7) + 8);  // covers trip+1 + margin
        if (tid < ALG_DIM) {
            cnt[tid * CNT_STRIDE] = sz;
            const size_t base = (size_t)tid << 8;
            for (int e = min(sz, CAP); e < E; ++e)
                packed[base + e] = make_uint2(0u, 0u);
        }
    }
}

// ---------- main: plane-layout f16 gather, packed FMA, windowed fp32 flush ----
// (byte-for-byte the round-1 kernel: verified, 0 bank conflicts, LDS-bound)
// 256 threads = 64 streams x 4 lanes over 32 rows x 62 slots. x,y in LDS as
// f16 in 4 planes: (col i, rows 8s..8s+7) at byte s*3984 + i*16. Lane q folds
// q*3984 into its base pointer once; gather = ds_read_b128 at base + i*16.
// Body: 12 VALU/triple + 2 b128. f16 accs flushed to fp32 every 32 triples.
// trip = round8(wave-max of 16 stream sizes) via 4x shfl_xor.

__global__ __launch_bounds__(256, 4) void k_main(
    const float* __restrict__ x, const float* __restrict__ y,
    const uint4* __restrict__ packed4,
    const int* __restrict__ cnt,
    const float* __restrict__ alpha_p, float* __restrict__ out)
{
    __shared__ __align__(16) unsigned xs32[4 * PLSTRIDE_DW];
    __shared__ __align__(16) unsigned ys32[4 * PLSTRIDE_DW];

    const int tid = threadIdx.x;
    const int r0  = blockIdx.x * ROWS;

    for (int u = tid; u < (ALG_DIM / 4) * (ROWS / 2); u += 256) {
        const int rp = u & 15;
        const int cq = u >> 4;
        const size_t ra = (size_t)(r0 + 2 * rp) * ALG_DIM + 4 * cq;
        const float4 xa = *reinterpret_cast<const float4*>(x + ra);
        const float4 xb = *reinterpret_cast<const float4*>(x + ra + ALG_DIM);
        const float4 ya = *reinterpret_cast<const float4*>(y + ra);
        const float4 yb = *reinterpret_cast<const float4*>(y + ra + ALG_DIM);
        const int pbase = (rp >> 2) * PLSTRIDE_DW + (rp & 3);
#define STG(d, XA, XB, YA, YB)                                                  \
        {                                                                       \
            const int dw = pbase + (4 * cq + (d)) * 4;                          \
            H2U hx; hx.h = __builtin_amdgcn_cvt_pkrtz(XA, XB);                  \
            H2U hy; hy.h = __builtin_amdgcn_cvt_pkrtz(YA, YB);                  \
            xs32[dw] = hx.u;                                                    \
            ys32[dw] = hy.u;                                                    \
        }
        STG(0, xa.x, xb.x, ya.x, yb.x)
        STG(1, xa.y, xb.y, ya.y, yb.y)
        STG(2, xa.z, xb.z, ya.z, yb.z)
        STG(3, xa.w, xb.w, ya.w, yb.w)
#undef STG
    }
    __syncthreads();

    const float alpha = alpha_p[0];
    const int   S     = tid >> 2;            // stream 0..63 (owns one slot)
    const int   q     = tid & 3;             // my plane (rows 8q..8q+7)

    const char* xsb = reinterpret_cast<const char*>(xs32) + q * PLSTRIDE_B;
    const char* ysb = reinterpret_cast<const char*>(ys32) + q * PLSTRIDE_B;

    // per-stream bucket size; wave-max over the 16 streams of this wave.
    // Computed by ALL lanes (streams >= KPB contribute 0) so the shuffles
    // run fully converged.
    const int p   = blockIdx.y * KPB + S;
    int m = (S < KPB) ? cnt[p * CNT_STRIDE] : 0;
    m = max(m, __shfl_xor(m, 4));
    m = max(m, __shfl_xor(m, 8));
    m = max(m, __shfl_xor(m, 16));
    m = max(m, __shfl_xor(m, 32));
    const int trip = __builtin_amdgcn_readfirstlane(min((m + 7) & ~7, CAP - 8));
    const int nH   = trip >> 1;              // uint4s (2 triples each)

    if (S < KPB) {
        const int k = p;                     // identity perm
        const uint4* tp = packed4 + ((size_t)p << 7);   // 128 uint4 per bucket

        float a0 = 0.f, a1 = 0.f, a2 = 0.f, a3 = 0.f,
              a4 = 0.f, a5 = 0.f, a6 = 0.f, a7 = 0.f;

        uint4 cur = tp[0];

#define PROC(PW, PC)                                                            \
        {                                                                       \
            const unsigned ox = (PW) & 0xFFFFu;                                 \
            const unsigned oy = (PW) >> 16;                                     \
            const uint4 wx = *reinterpret_cast<const uint4*>(xsb + ox);         \
            const uint4 wy = *reinterpret_cast<const uint4*>(ysb + oy);         \
            H2U cc; cc.u = (PC);                                                \
            H2U ux, uy;                                                         \
            ux.u = wx.x; uy.u = wy.x; c0 = (ux.h * uy.h) * cc.h + c0;           \
            ux.u = wx.y; uy.u = wy.y; c1 = (ux.h * uy.h) * cc.h + c1;           \
            ux.u = wx.z; uy.u = wy.z; c2 = (ux.h * uy.h) * cc.h + c2;           \
            ux.u = wx.w; uy.u = wy.w; c3 = (ux.h * uy.h) * cc.h + c3;           \
        }

        for (int chunk = 0; chunk < nH; chunk += 16) {       // 32-triple window
            h2v c0 = (h2v)0.0f, c1 = (h2v)0.0f, c2 = (h2v)0.0f, c3 = (h2v)0.0f;
            const int hend = min(chunk + 16, nH);
#pragma unroll 2
            for (int h = chunk; h < hend; ++h) {
                const uint4 nxt = tp[h + 1];  // prefetch (zeroed tail covers over-read)
                PROC(cur.x, cur.y)
                PROC(cur.z, cur.w)
                cur = nxt;
            }
            a0 += (float)c0.x; a1 += (float)c0.y;
            a2 += (float)c1.x; a3 += (float)c1.y;
            a4 += (float)c2.x; a5 += (float)c2.y;
            a6 += (float)c3.x; a7 += (float)c3.y;
        }
#undef PROC

        const int rbase = r0 + (q << 3);
        out[(size_t)(rbase + 0) * ALG_DIM + k] = alpha * a0;
        out[(size_t)(rbase + 1) * ALG_DIM + k] = alpha * a1;
        out[(size_t)(rbase + 2) * ALG_DIM + k] = alpha * a2;
        out[(size_t)(rbase + 3) * ALG_DIM + k] = alpha * a3;
        out[(size_t)(rbase + 4) * ALG_DIM + k] = alpha * a4;
        out[(size_t)(rbase + 5) * ALG_DIM + k] = alpha * a5;
        out[(size_t)(rbase + 6) * ALG_DIM + k] = alpha * a6;
        out[(size_t)(rbase + 7) * ALG_DIM + k] = alpha * a7;
    }
}

// ---------- launch: exactly TWO nodes, no memset ----------

extern "C" void kernel_launch(void* const* d_in, const int* in_sizes, int n_in,
                              void* d_out, int out_size, void* d_ws, size_t ws_size,
                              hipStream_t stream) {
    const float* x      = (const float*)d_in[0];
    const float* y      = (const float*)d_in[1];
    const int*   idx_i  = (const int*)d_in[2];
    const int*   idx_j  = (const int*)d_in[3];
    const int*   idx_k  = (const int*)d_in[4];
    const float* coeff  = (const float*)d_in[5];
    const float* alpha  = (const float*)d_in[6];
    float*       out    = (float*)d_out;

    const int nnz   = in_sizes[2];
    const int batch = in_sizes[0] / ALG_DIM;

    // ws: [cnt @0, 16 KB][packed @16384, 248*256*8 = 507904 B]
    char*  ws     = (char*)d_ws;
    int*   cnt    = (int*)ws;
    uint2* packed = (uint2*)(ws + 16384);

    k_prep<<<CB, 256, 0, stream>>>(idx_i, idx_j, idx_k, coeff, cnt, packed, nnz);

    dim3 grid(batch / ROWS, KSPLIT);
    k_main<<<grid, 256, 0, stream>>>(x, y, (const uint4*)packed, cnt, alpha, out);
}

// Round 5
// 113.890 us; speedup vs baseline: 1.3212x; 1.2186x over previous
//
#include <hip/hip_runtime.h>

#define ALG_DIM 248
#define ROWS 32                    // rows per main-kernel block
#define KSPLIT 4
#define KPB 62                     // k-slots per block (248/4)
#define CAP 256                    // uint2 capacity per bucket (pow2; max bucket ~160)
#define CNT_STRIDE 16              // ints between cnt entries (64 B)
#define PLSTRIDE_B 3984            // plane stride bytes (248*16 + 16; /4 = 996 ≡ 4 mod 32)
#define PLSTRIDE_DW 996

typedef __fp16 h2v __attribute__((ext_vector_type(2)));
union H2U { unsigned u; h2v h; };

// ---------- prep: ONE kernel, 2 nodes total, no memset ----------
// Prefix-scan scatter, SOFTWARE-PIPELINED (round-4 fix: the scalar
// load->atomic chain was HBM-latency-bound at 50 us; now 8 int4 loads
// (32 elems) are issued independently per step, then the 32 LDS atomics).
// Chunk = 1024 elems -> prefix ranges are int4-exact.
//   phase 1: batched prefix histogram of idx_k[0, lo_b) into LDS cursors
//            seeded with bucket bases (cur[k] = k*CAP). Private per block,
//            no global state consumed => poison-safe with zero pre-init.
//   phase 2: scatter own chunk [lo_b, hi_b) via LDS atomicAdd. Every block
//            writes an exact, disjoint position range per bucket (base +
//            prefix count) -> no gaps, no overflow, no global atomics.
//   phase 3 (last block): cur[k]-k*CAP == final bucket sizes. Zero bucket
//            tails [sz, E) (beyond all scatter writes -> race-free) and
//            store cnt[k]. Zero tail entries are exact no-ops in k_main.

__global__ __launch_bounds__(256) void k_prep(
    const int* __restrict__ idx_i, const int* __restrict__ idx_j,
    const int* __restrict__ idx_k, const float* __restrict__ coeff,
    int* __restrict__ cnt, uint2* __restrict__ packed, int nnz)
{
    __shared__ int cur[256];
    __shared__ int red[256];
    const int tid = threadIdx.x;
    const int b   = blockIdx.x;
    const int nb  = gridDim.x;

    cur[tid] = tid * CAP;                      // bucket base seeds
    __syncthreads();

    const int lo = b << 10;                    // b * 1024 (int4-aligned)
    const int hi = min(nnz, lo + 1024);

    // ---- phase-2 loads issued EARLY (no LDS dependence; hide under phase 1)
    int mk[4], mi[4], mj[4]; float mc[4];
#pragma unroll
    for (int u = 0; u < 4; ++u) {
        const int t = lo + (u << 8) + tid;
        if (t < hi) { mk[u] = idx_k[t]; mi[u] = idx_i[t]; mj[u] = idx_j[t]; mc[u] = coeff[t]; }
        else mk[u] = -1;
    }

    // ---- phase 1: batched prefix histogram over [0, lo) ----
    const int nI4 = lo >> 2;                   // exact (lo multiple of 1024)
    const int4* k4 = reinterpret_cast<const int4*>(idx_k);
    for (int base = 0; base < nI4; base += 2048) {      // 8192 elems / super-iter
        int4 v[8];
#pragma unroll
        for (int u = 0; u < 8; ++u) {                   // 8 independent loads
            const int t4 = base + (u << 8) + tid;
            v[u] = (t4 < nI4) ? k4[t4] : make_int4(-1, -1, -1, -1);
        }
#pragma unroll
        for (int u = 0; u < 8; ++u) {
            if (v[u].x >= 0) {
                atomicAdd(&cur[v[u].x], 1); atomicAdd(&cur[v[u].y], 1);
                atomicAdd(&cur[v[u].z], 1); atomicAdd(&cur[v[u].w], 1);
            }
        }
    }
    __syncthreads();                           // all prefix adds before scatter

    // ---- phase 2: scatter own chunk (exact disjoint position ranges) ----
#pragma unroll
    for (int u = 0; u < 4; ++u) {
        if (mk[u] >= 0) {
            const int pos = atomicAdd(&cur[mk[u]], 1);
            if (pos < (mk[u] + 1) * CAP) {     // structurally unreachable guard
                H2U hc; hc.h = __builtin_amdgcn_cvt_pkrtz(mc[u], mc[u]);
                uint2 p;
                p.x = ((unsigned)mi[u] << 4) | ((unsigned)mj[u] << 20);
                p.y = hc.u;
                packed[pos] = p;
            }
        }
    }

    // ---- phase 3: last block tail-zeroes + publishes sizes ----
    if (b == nb - 1) {
        __syncthreads();
        const int sz = (tid < ALG_DIM) ? (cur[tid] - tid * CAP) : 0;
        red[tid] = sz;
        __syncthreads();
        for (int off = 128; off > 0; off >>= 1) {
            if (tid < off) red[tid] = max(red[tid], red[tid + off]);
            __syncthreads();
        }
        const int E = min(CAP, ((red[0] + 7) & ~7) + 8);   // covers trip + prefetch
        if (tid < ALG_DIM) {
            cnt[tid * CNT_STRIDE] = sz;
            const size_t basep = (size_t)tid << 8;
            for (int e = min(sz, CAP); e < E; ++e)
                packed[basep + e] = make_uint2(0u, 0u);
        }
    }
}

// ---------- main: plane-layout f16 gather, packed FMA, windowed fp32 flush ----
// (byte-for-byte the round-1 kernel: verified, 0 bank conflicts)
// 256 threads = 64 streams x 4 lanes over 32 rows x 62 slots. x,y in LDS as
// f16 in 4 planes: (col i, rows 8s..8s+7) at byte s*3984 + i*16. Lane q folds
// q*3984 into its base pointer once; gather = ds_read_b128 at base + i*16.
// Body: 12 VALU/triple + 2 b128. f16 accs flushed to fp32 every 32 triples.
// trip = round8(wave-max of 16 stream sizes) via 4x shfl_xor.

__global__ __launch_bounds__(256, 4) void k_main(
    const float* __restrict__ x, const float* __restrict__ y,
    const uint4* __restrict__ packed4,
    const int* __restrict__ cnt,
    const float* __restrict__ alpha_p, float* __restrict__ out)
{
    __shared__ __align__(16) unsigned xs32[4 * PLSTRIDE_DW];
    __shared__ __align__(16) unsigned ys32[4 * PLSTRIDE_DW];

    const int tid = threadIdx.x;
    const int r0  = blockIdx.x * ROWS;

    for (int u = tid; u < (ALG_DIM / 4) * (ROWS / 2); u += 256) {
        const int rp = u & 15;
        const int cq = u >> 4;
        const size_t ra = (size_t)(r0 + 2 * rp) * ALG_DIM + 4 * cq;
        const float4 xa = *reinterpret_cast<const float4*>(x + ra);
        const float4 xb = *reinterpret_cast<const float4*>(x + ra + ALG_DIM);
        const float4 ya = *reinterpret_cast<const float4*>(y + ra);
        const float4 yb = *reinterpret_cast<const float4*>(y + ra + ALG_DIM);
        const int pbase = (rp >> 2) * PLSTRIDE_DW + (rp & 3);
#define STG(d, XA, XB, YA, YB)                                                  \
        {                                                                       \
            const int dw = pbase + (4 * cq + (d)) * 4;                          \
            H2U hx; hx.h = __builtin_amdgcn_cvt_pkrtz(XA, XB);                  \
            H2U hy; hy.h = __builtin_amdgcn_cvt_pkrtz(YA, YB);                  \
            xs32[dw] = hx.u;                                                    \
            ys32[dw] = hy.u;                                                    \
        }
        STG(0, xa.x, xb.x, ya.x, yb.x)
        STG(1, xa.y, xb.y, ya.y, yb.y)
        STG(2, xa.z, xb.z, ya.z, yb.z)
        STG(3, xa.w, xb.w, ya.w, yb.w)
#undef STG
    }
    __syncthreads();

    const float alpha = alpha_p[0];
    const int   S     = tid >> 2;            // stream 0..63 (owns one slot)
    const int   q     = tid & 3;             // my plane (rows 8q..8q+7)

    const char* xsb = reinterpret_cast<const char*>(xs32) + q * PLSTRIDE_B;
    const char* ysb = reinterpret_cast<const char*>(ys32) + q * PLSTRIDE_B;

    // per-stream bucket size; wave-max over the 16 streams of this wave.
    // Computed by ALL lanes (streams >= KPB contribute 0) so the shuffles
    // run fully converged.
    const int p   = blockIdx.y * KPB + S;
    int m = (S < KPB) ? cnt[p * CNT_STRIDE] : 0;
    m = max(m, __shfl_xor(m, 4));
    m = max(m, __shfl_xor(m, 8));
    m = max(m, __shfl_xor(m, 16));
    m = max(m, __shfl_xor(m, 32));
    const int trip = __builtin_amdgcn_readfirstlane(min((m + 7) & ~7, CAP - 8));
    const int nH   = trip >> 1;              // uint4s (2 triples each)

    if (S < KPB) {
        const int k = p;                     // identity perm
        const uint4* tp = packed4 + ((size_t)p << 7);   // 128 uint4 per bucket

        float a0 = 0.f, a1 = 0.f, a2 = 0.f, a3 = 0.f,
              a4 = 0.f, a5 = 0.f, a6 = 0.f, a7 = 0.f;

        uint4 cur = tp[0];

#define PROC(PW, PC)                                                            \
        {                                                                       \
            const unsigned ox = (PW) & 0xFFFFu;                                 \
            const unsigned oy = (PW) >> 16;                                     \
            const uint4 wx = *reinterpret_cast<const uint4*>(xsb + ox);         \
            const uint4 wy = *reinterpret_cast<const uint4*>(ysb + oy);         \
            H2U cc; cc.u = (PC);                                                \
            H2U ux, uy;                                                         \
            ux.u = wx.x; uy.u = wy.x; c0 = (ux.h * uy.h) * cc.h + c0;           \
            ux.u = wx.y; uy.u = wy.y; c1 = (ux.h * uy.h) * cc.h + c1;           \
            ux.u = wx.z; uy.u = wy.z; c2 = (ux.h * uy.h) * cc.h + c2;           \
            ux.u = wx.w; uy.u = wy.w; c3 = (ux.h * uy.h) * cc.h + c3;           \
        }

        for (int chunk = 0; chunk < nH; chunk += 16) {       // 32-triple window
            h2v c0 = (h2v)0.0f, c1 = (h2v)0.0f, c2 = (h2v)0.0f, c3 = (h2v)0.0f;
            const int hend = min(chunk + 16, nH);
#pragma unroll 2
            for (int h = chunk; h < hend; ++h) {
                const uint4 nxt = tp[h + 1];  // prefetch (zeroed tail covers over-read)
                PROC(cur.x, cur.y)
                PROC(cur.z, cur.w)
                cur = nxt;
            }
            a0 += (float)c0.x; a1 += (float)c0.y;
            a2 += (float)c1.x; a3 += (float)c1.y;
            a4 += (float)c2.x; a5 += (float)c2.y;
            a6 += (float)c3.x; a7 += (float)c3.y;
        }
#undef PROC

        const int rbase = r0 + (q << 3);
        out[(size_t)(rbase + 0) * ALG_DIM + k] = alpha * a0;
        out[(size_t)(rbase + 1) * ALG_DIM + k] = alpha * a1;
        out[(size_t)(rbase + 2) * ALG_DIM + k] = alpha * a2;
        out[(size_t)(rbase + 3) * ALG_DIM + k] = alpha * a3;
        out[(size_t)(rbase + 4) * ALG_DIM + k] = alpha * a4;
        out[(size_t)(rbase + 5) * ALG_DIM + k] = alpha * a5;
        out[(size_t)(rbase + 6) * ALG_DIM + k] = alpha * a6;
        out[(size_t)(rbase + 7) * ALG_DIM + k] = alpha * a7;
    }
}

// ---------- launch: exactly TWO nodes, no memset ----------

extern "C" void kernel_launch(void* const* d_in, const int* in_sizes, int n_in,
                              void* d_out, int out_size, void* d_ws, size_t ws_size,
                              hipStream_t stream) {
    const float* x      = (const float*)d_in[0];
    const float* y      = (const float*)d_in[1];
    const int*   idx_i  = (const int*)d_in[2];
    const int*   idx_j  = (const int*)d_in[3];
    const int*   idx_k  = (const int*)d_in[4];
    const float* coeff  = (const float*)d_in[5];
    const float* alpha  = (const float*)d_in[6];
    float*       out    = (float*)d_out;

    const int nnz   = in_sizes[2];
    const int batch = in_sizes[0] / ALG_DIM;

    // ws: [cnt @0, 16 KB][packed @16384, 248*256*8 = 507904 B]
    char*  ws     = (char*)d_ws;
    int*   cnt    = (int*)ws;
    uint2* packed = (uint2*)(ws + 16384);

    const int nb = (nnz + 1023) >> 10;         // 1024-elem chunks
    k_prep<<<nb, 256, 0, stream>>>(idx_i, idx_j, idx_k, coeff, cnt, packed, nnz);

    dim3 grid(batch / ROWS, KSPLIT);
    k_main<<<grid, 256, 0, stream>>>(x, y, (const uint4*)packed, cnt, alpha, out);
}